// Round 1
// baseline (719.587 us; speedup 1.0000x reference)
//
#include <hip/hip_runtime.h>

#define NBINS 15
#define NCLS  100
#define NSEG  (NBINS * NCLS)   // 1500
#define MAXBLK 1024
#define NGRP  16               // second-stage reduction groups

// Kernel 1: stream probas, accumulate per-block histograms in LDS,
// write per-block partials (no global atomics).
__global__ __launch_bounds__(256) void calib_accum(
    const float* __restrict__ probas,
    const int*   __restrict__ labels,
    float*       __restrict__ partA,   // [nblk][3*NSEG]
    int total4)
{
    __shared__ float s_cnt[NSEG];
    __shared__ float s_sum[NSEG];
    __shared__ float s_acc[NSEG];
    for (int i = threadIdx.x; i < NSEG; i += 256) {
        s_cnt[i] = 0.f; s_sum[i] = 0.f; s_acc[i] = 0.f;
    }
    __syncthreads();

    const float4* __restrict__ p4 = (const float4*)probas;
    const float inv15 = 1.0f / 15.0f;
    const int stride = gridDim.x * 256;

    for (int i = blockIdx.x * 256 + threadIdx.x; i < total4; i += stride) {
        float4 v = p4[i];
        // flat = 4*i; row = flat/100 = i/25; col = (i%25)*4  (never crosses a row)
        int row = i / 25;
        int col = (i - row * 25) * 4;
        int lbl = labels[row];
        float pv[4] = {v.x, v.y, v.z, v.w};
        #pragma unroll
        for (int j = 0; j < 4; ++j) {
            float p = pv[j];
            int c = col + j;
            // searchsorted(bins, p, 'right') - 1: largest k with bins[k] <= p
            int k = (int)(p * 15.0f);
            if (k < NBINS && (float)(k + 1) * inv15 <= p)      ++k;
            else if (k > 0 && (float)k * inv15 > p)            --k;
            float left = (float)k * inv15;
            // valid: p > threshold, 0 <= k < NBINS (k>=0 automatic), p strictly > left edge
            if (p > 0.01f && k < NBINS && p > left) {
                int seg = c * NBINS + k;
                atomicAdd(&s_cnt[seg], 1.0f);
                atomicAdd(&s_sum[seg], p);
                if (lbl == c) atomicAdd(&s_acc[seg], 1.0f);
            }
        }
    }
    __syncthreads();

    float* dst = partA + (size_t)blockIdx.x * (3 * NSEG);
    for (int s = threadIdx.x; s < NSEG; s += 256) {
        dst[s]            = s_cnt[s];
        dst[NSEG + s]     = s_sum[s];
        dst[2 * NSEG + s] = s_acc[s];
    }
}

// Kernel 2: 16-way parallel partial reduction over blocks (coalesced on s).
__global__ __launch_bounds__(256) void calib_mid(
    const float* __restrict__ partA, int nblk, int chunk,
    float*       __restrict__ partB)   // [NGRP][3*NSEG]
{
    int t = blockIdx.x * 256 + threadIdx.x;
    if (t >= NGRP * NSEG) return;
    int g = t / NSEG;
    int s = t - g * NSEG;
    int b0 = g * chunk;
    int b1 = b0 + chunk; if (b1 > nblk) b1 = nblk;
    float cnt = 0.f, sum = 0.f, acc = 0.f;
    for (int b = b0; b < b1; ++b) {
        const float* src = partA + (size_t)b * (3 * NSEG);
        cnt += src[s];
        sum += src[NSEG + s];
        acc += src[2 * NSEG + s];
    }
    float* dst = partB + (size_t)g * (3 * NSEG);
    dst[s]            = cnt;
    dst[NSEG + s]     = sum;
    dst[2 * NSEG + s] = acc;
}

// Kernel 3: final sum over NGRP groups, divide, NaN for empty bins.
__global__ __launch_bounds__(256) void calib_fin(
    const float* __restrict__ partB,
    float*       __restrict__ out)     // [confs(1500), accs(1500), n_samples(1500)]
{
    int s = blockIdx.x * 256 + threadIdx.x;
    if (s >= NSEG) return;
    float cnt = 0.f, sum = 0.f, acc = 0.f;
    #pragma unroll
    for (int g = 0; g < NGRP; ++g) {
        const float* src = partB + g * (3 * NSEG);
        cnt += src[s];
        sum += src[NSEG + s];
        acc += src[2 * NSEG + s];
    }
    float conf, accv;
    if (cnt > 0.f) { conf = sum / cnt; accv = acc / cnt; }
    else { conf = __int_as_float(0x7fc00000); accv = conf; }
    out[s]            = conf;
    out[NSEG + s]     = accv;
    out[2 * NSEG + s] = cnt;
}

extern "C" void kernel_launch(void* const* d_in, const int* in_sizes, int n_in,
                              void* d_out, int out_size, void* d_ws, size_t ws_size,
                              hipStream_t stream) {
    const float* probas = (const float*)d_in[0];
    const int*   labels = (const int*)d_in[1];
    float* out = (float*)d_out;
    float* ws  = (float*)d_ws;

    int total  = in_sizes[0];      // N*C = 50,000,000 (divisible by 4)
    int total4 = total / 4;

    // workspace: partA [nblk][3*NSEG] followed by partB [NGRP][3*NSEG]
    size_t ws_floats = ws_size / sizeof(float);
    long long avail = (long long)ws_floats - (long long)NGRP * 3 * NSEG;
    int nblk = (int)(avail / (3 * NSEG));
    if (nblk > MAXBLK) nblk = MAXBLK;
    if (nblk < 1) nblk = 1;

    float* partA = ws;
    float* partB = ws + (size_t)nblk * (3 * NSEG);

    calib_accum<<<nblk, 256, 0, stream>>>(probas, labels, partA, total4);
    int chunk = (nblk + NGRP - 1) / NGRP;
    calib_mid<<<(NGRP * NSEG + 255) / 256, 256, 0, stream>>>(partA, nblk, chunk, partB);
    calib_fin<<<(NSEG + 255) / 256, 256, 0, stream>>>(partB, out);
}